// Round 4
// baseline (416.167 us; speedup 1.0000x reference)
//
#include <hip/hip_runtime.h>

typedef __attribute__((ext_vector_type(8))) short short8;
typedef __attribute__((ext_vector_type(4))) float f32x4;

#define NN 8192
#define DD 64

// f32 -> bf16 RNE (used only for the internal y staging)
__device__ inline unsigned short f2bf(float f){
  unsigned b = __float_as_uint(f);
  b = (b + 0x7fffu + ((b >> 16) & 1u)) >> 16;
  return (unsigned short)b;
}

// ---------------------------------------------------------------------------
// Confirmed (R3 pass): inputs f32, output f32, threshold 1.78, absmax 0.5.
// Algebra: softmax rows sum to 1 -> attn_agg == aggregated; Wa_* unused.
//   out = x@(Wobj+Wskip) + r@Wrel + A^T @ (x@Wnobj + bnobj) + (bobj+brel+bskip)
// A is exactly 0/1 -> f32->bf16 truncation EXACT -> bf16 MFMA for A^T y.
//
// R4 change: kill the 8.4M contended fp32 atomicAdds (suspected ~250+ us of
// the 409) -> disjoint per-kb partial planes + fused reduction in k_out.
// ---------------------------------------------------------------------------

// Kernel 1: per-row projections.
//   accT[d][i] = x@(Wobj+Wskip) + r@Wrel + (bobj+brel+bskip)   (f32 [64][8192])
//   yT[d][i]   = bf16( x@Wnobj + bnobj )                       (bf16 [64][8192])
__global__ __launch_bounds__(256) void k_proj(
    const float* __restrict__ x, const float* __restrict__ r,
    const float* __restrict__ Wobj,  const float* __restrict__ bobj,
    const float* __restrict__ Wnobj, const float* __restrict__ bnobj,
    const float* __restrict__ Wrel,  const float* __restrict__ brel,
    const float* __restrict__ Wskip, const float* __restrict__ bskip,
    float* __restrict__ accT, unsigned short* __restrict__ yT)
{
  const int i  = blockIdx.x * 256 + threadIdx.x;   // row
  const int d0 = blockIdx.y * 8;                   // this block's 8 output dims

  float xv[DD], rv[DD];
  const float4* xp = (const float4*)(x + i * DD);
  const float4* rp = (const float4*)(r + i * DD);
#pragma unroll
  for (int p = 0; p < 16; p++){
    float4 u = xp[p];
    xv[4*p+0]=u.x; xv[4*p+1]=u.y; xv[4*p+2]=u.z; xv[4*p+3]=u.w;
    float4 v = rp[p];
    rv[4*p+0]=v.x; rv[4*p+1]=v.y; rv[4*p+2]=v.z; rv[4*p+3]=v.w;
  }

  float ay[8], az[8];
#pragma unroll
  for (int t = 0; t < 8; t++){ ay[t] = 0.f; az[t] = 0.f; }

  // weights are wave-uniform -> s_loads; full unroll keeps xv/rv reg-indexed
#pragma unroll
  for (int k = 0; k < DD; k++){
    const float xk = xv[k], rk = rv[k];
    const int wb = k * DD + d0;
#pragma unroll
    for (int t = 0; t < 8; t++){
      ay[t] += xk * Wnobj[wb + t];
      az[t] += xk * Wobj [wb + t];
      az[t] += xk * Wskip[wb + t];
      az[t] += rk * Wrel [wb + t];
    }
  }

#pragma unroll
  for (int t = 0; t < 8; t++){
    ay[t] += bnobj[d0 + t];
    az[t] += bobj[d0 + t] + brel[d0 + t] + bskip[d0 + t];
    yT[(d0 + t) * NN + i]   = f2bf(ay[t]);   // coalesced: lanes = consecutive i
    accT[(d0 + t) * NN + i] = az[t];
  }
}

// ---------------------------------------------------------------------------
// Kernel 2: part[kb][d][j] = sum_{k in chunk kb} yT[d][k] * A[k][j]
// MFMA 16x16x32 bf16. M=64 (d), N=8192 (j), K=8192. Split-K=16, NO atomics:
// each (jb,kb) block owns a disjoint 64x128 region of plane kb.
// XOR-chunk swizzle keeps the k-strided B-frag ds_read_u16s 2-way (free).
// ---------------------------------------------------------------------------
#define BN 128
#define KSPLIT 16
#define KCH (NN / KSPLIT)   // 512
#define NIT (KCH / 64)      // 8

__global__ __launch_bounds__(256) void k_spmm(
    const float* __restrict__ A,
    const unsigned short* __restrict__ yT,
    float* __restrict__ part)
{
  __shared__ short Alds[64 * 128];   // [k][j swizzled], row pitch 128 elems (256B)
  __shared__ short Ylds[64 * 72];    // [d][k], pitch 72 (conflict-free b128)

  const int tid  = threadIdx.x;
  const int lane = tid & 63;
  const int wave = tid >> 6;
  const int q    = lane >> 4;    // k-quad within fragment
  const int nn   = lane & 15;    // m (A-frag) / n (B-frag, C col) index

  const int j0     = blockIdx.x * BN;
  const int kstart = blockIdx.y * KCH;

  // A staging coords: 4 f32 columns (16B) per load
  const int c4 = tid & 31;       // 4-col chunk within 128-col row
  const int kr = tid >> 5;       // rows kr + p*8, p = 0..7
  // y staging coords
  const int cY = tid & 7;        // 16B chunk within 128B y row
  const int m0 = tid >> 3;       // y rows m0 + {0,32}

  uint4 abuf[8], ybuf[2];
  auto gload = [&](int it){
    const int kbase = kstart + it * 64;
#pragma unroll
    for (int p = 0; p < 8; p++)
      abuf[p] = *(const uint4*)(A + (size_t)(kbase + kr + p*8) * NN + j0 + c4 * 4);
#pragma unroll
    for (int p = 0; p < 2; p++)
      ybuf[p] = *(const uint4*)(yT + (m0 + p*32) * NN + kbase + cY * 8);
  };

  f32x4 acc[4][2];
#pragma unroll
  for (int a = 0; a < 4; a++)
#pragma unroll
    for (int b = 0; b < 2; b++)
      acc[a][b] = (f32x4){0.f, 0.f, 0.f, 0.f};

  gload(0);
  for (int it = 0; it < NIT; ++it){
    __syncthreads();               // previous compute done; LDS reusable
#pragma unroll
    for (int p = 0; p < 8; p++){
      const int kk  = kr + p*8;
      const int key = 2 * (p & 3);                 // == 2*((kk>>3)&3), kr<8
      // exact f32->bf16 truncation (A is 0/1), packed 2 at a time
      unsigned lo = (abuf[p].y & 0xFFFF0000u) | (abuf[p].x >> 16);
      unsigned hi = (abuf[p].w & 0xFFFF0000u) | (abuf[p].z >> 16);
      const int off = kk * 128 + (((c4 >> 1) ^ key) * 8) + (c4 & 1) * 4;
      *(uint2*)(&Alds[off]) = make_uint2(lo, hi);  // 8B aligned
    }
#pragma unroll
    for (int p = 0; p < 2; p++)
      *(uint4*)(&Ylds[(m0 + p*32) * 72 + cY * 8]) = ybuf[p];
    __syncthreads();
    if (it + 1 < NIT) gload(it + 1);   // prefetch overlaps MFMA below

#pragma unroll
    for (int ks = 0; ks < 2; ks++){
      short8 af[4];
#pragma unroll
      for (int mt = 0; mt < 4; mt++)    // A-frag: yT[m=16mt+nn][k = ks*32+q*8 ..+7]
        af[mt] = *(const short8*)(&Ylds[(mt*16 + nn) * 72 + ks*32 + q*8]);
#pragma unroll
      for (int nt = 0; nt < 2; nt++){
        const int col = wave * 32 + nt * 16 + nn;
        // B-frag: A[k = ks*32+q*8+jj][col]; swizzle key (k>>3)&3 == q for jj<8
        const short* bp = &Alds[(ks*32 + q*8) * 128
                                + (((col >> 3) ^ (2*q)) * 8) + (col & 7)];
        short8 bf;
#pragma unroll
        for (int jj = 0; jj < 8; jj++) bf[jj] = bp[jj * 128];  // imm-offset u16s
#pragma unroll
        for (int mt = 0; mt < 4; mt++)
          acc[mt][nt] = __builtin_amdgcn_mfma_f32_16x16x32_bf16(af[mt], bf, acc[mt][nt], 0, 0, 0);
      }
    }
  }

  // epilogue: C/D layout col=lane&15, row=q*4+reg. Disjoint region -> plain
  // stores (64B segments x 4 rows per v); zero atomics.
  float* pp = part + (size_t)blockIdx.y * DD * NN;
#pragma unroll
  for (int mt = 0; mt < 4; mt++)
#pragma unroll
    for (int nt = 0; nt < 2; nt++)
#pragma unroll
      for (int v = 0; v < 4; v++){
        const int d   = mt * 16 + q * 4 + v;
        const int col = j0 + wave * 32 + nt * 16 + nn;
        pp[d * NN + col] = acc[mt][nt][v];
      }
}

// ---------------------------------------------------------------------------
// Kernel 3: out[j][d] = accT[d][j] + sum_kb part[kb][d][j]  (f32, LDS transpose)
// 256 blocks x 32 j-cols: both read and write sides fully coalesced.
// ---------------------------------------------------------------------------
__global__ __launch_bounds__(256) void k_out(
    const float* __restrict__ accT, const float* __restrict__ part,
    float* __restrict__ out)
{
  __shared__ float t[64][33];      // pitch 33: both phases 2-way (free)
  const int tid = threadIdx.x;
  const int jb  = blockIdx.x * 32;

#pragma unroll
  for (int rep = 0; rep < 8; rep++){
    const int d = rep * 8 + (tid >> 5);
    const int j = tid & 31;
    const size_t base = (size_t)d * NN + jb + j;
    float s = accT[base];
#pragma unroll
    for (int kb = 0; kb < KSPLIT; kb++)
      s += part[(size_t)kb * DD * NN + base];   // 128B segments per row
    t[d][j] = s;
  }
  __syncthreads();
#pragma unroll
  for (int rep = 0; rep < 8; rep++){
    const int j = rep * 4 + (tid >> 6);
    const int d = tid & 63;
    out[(size_t)(jb + j) * DD + d] = t[d][j];   // 256B contiguous per wave
  }
}

extern "C" void kernel_launch(void* const* d_in, const int* in_sizes, int n_in,
                              void* d_out, int out_size, void* d_ws, size_t ws_size,
                              hipStream_t stream) {
  const float* x     = (const float*)d_in[0];
  const float* r     = (const float*)d_in[1];
  const float* A     = (const float*)d_in[2];
  const float* Wobj  = (const float*)d_in[3];
  const float* bobj  = (const float*)d_in[4];
  const float* Wnobj = (const float*)d_in[5];
  const float* bnobj = (const float*)d_in[6];
  const float* Wrel  = (const float*)d_in[7];
  const float* brel  = (const float*)d_in[8];
  const float* Wskip = (const float*)d_in[9];
  const float* bskip = (const float*)d_in[10];
  // d_in[11] (Wa_w) and d_in[12] (Wa_b) are provably unused: softmax rows sum to 1.

  char* ws = (char*)d_ws;
  float* accT        = (float*)ws;                                  // 2 MB @ 0
  unsigned short* yT = (unsigned short*)(ws + (size_t)DD*NN*4);     // 1 MB @ 2M
  float* part        = (float*)(ws + 3u*1024*1024);                 // 32 MB @ 3M

  k_proj<<<dim3(32, 8), 256, 0, stream>>>(x, r, Wobj, bobj, Wnobj, bnobj,
                                          Wrel, brel, Wskip, bskip, accT, yT);
  k_spmm<<<dim3(NN / BN, KSPLIT), 256, 0, stream>>>(A, yT, part);
  k_out<<<NN / 32, 256, 0, stream>>>(accT, part, (float*)d_out);
}

// Round 5
// 414.532 us; speedup vs baseline: 1.0039x; 1.0039x over previous
//
#include <hip/hip_runtime.h>

typedef __attribute__((ext_vector_type(8))) short short8;
typedef __attribute__((ext_vector_type(4))) float f32x4;

#define NN 8192
#define DD 64

// f32 -> bf16 RNE (internal y staging only)
__device__ inline unsigned short f2bf(float f){
  unsigned b = __float_as_uint(f);
  b = (b + 0x7fffu + ((b >> 16) & 1u)) >> 16;
  return (unsigned short)b;
}

// ---------------------------------------------------------------------------
// Confirmed: inputs f32, output f32, absmax 0.5 vs threshold 1.78.
// Algebra: softmax rows sum to 1 -> attn_agg == aggregated; Wa_* unused.
//   out = x@(Wobj+Wskip) + r@Wrel + A^T @ (x@Wnobj + bnobj) + (bobj+brel+bskip)
// A is exactly 0/1 -> f32->bf16 truncation EXACT -> bf16 MFMA for A^T y.
//
// R5: decomposition experiment. R3->R4 (+6.5us for +64MB traffic) proved
// atomics were ~free and deltas track pure traffic. Now push every kernel to
// its roofline: k_proj re-occupied (no reg-array spill risk), k_spmm
// double-buffered w/ 1 barrier per tile + KSPLIT 8, k_out 9 planes.
// ---------------------------------------------------------------------------

// Kernel 1: accT[d][i] = x@(Wobj+Wskip)+r@Wrel+biases ; yT[d][i]=bf16(x@Wnobj+bnobj)
// grid (32,16): 4 output dims per thread, 512 blocks (2/CU), small live arrays.
__global__ __launch_bounds__(256) void k_proj(
    const float* __restrict__ x, const float* __restrict__ r,
    const float* __restrict__ Wobj,  const float* __restrict__ bobj,
    const float* __restrict__ Wnobj, const float* __restrict__ bnobj,
    const float* __restrict__ Wrel,  const float* __restrict__ brel,
    const float* __restrict__ Wskip, const float* __restrict__ bskip,
    float* __restrict__ accT, unsigned short* __restrict__ yT)
{
  const int i  = blockIdx.x * 256 + threadIdx.x;   // row
  const int d0 = blockIdx.y * 4;                   // 4 output dims

  float ay[4] = {0.f,0.f,0.f,0.f}, az[4] = {0.f,0.f,0.f,0.f};
  const float4* xp = (const float4*)(x + (size_t)i * DD);
  const float4* rp = (const float4*)(r + (size_t)i * DD);

#pragma unroll
  for (int kb = 0; kb < 4; kb++){                  // 16 k per chunk
    float xv[16], rv[16];
#pragma unroll
    for (int p = 0; p < 4; p++){
      float4 u = xp[kb*4 + p];
      xv[4*p+0]=u.x; xv[4*p+1]=u.y; xv[4*p+2]=u.z; xv[4*p+3]=u.w;
      float4 v = rp[kb*4 + p];
      rv[4*p+0]=v.x; rv[4*p+1]=v.y; rv[4*p+2]=v.z; rv[4*p+3]=v.w;
    }
#pragma unroll
    for (int kk = 0; kk < 16; kk++){
      const int wb = (kb*16 + kk) * DD + d0;       // uniform -> s_loads
      const float xk = xv[kk], rk = rv[kk];
#pragma unroll
      for (int t = 0; t < 4; t++){
        ay[t] += xk * Wnobj[wb + t];
        az[t] += xk * Wobj [wb + t];
        az[t] += xk * Wskip[wb + t];
        az[t] += rk * Wrel [wb + t];
      }
    }
  }

#pragma unroll
  for (int t = 0; t < 4; t++){
    ay[t] += bnobj[d0 + t];
    az[t] += bobj[d0 + t] + brel[d0 + t] + bskip[d0 + t];
    yT[(size_t)(d0 + t) * NN + i]   = f2bf(ay[t]);   // coalesced
    accT[(size_t)(d0 + t) * NN + i] = az[t];
  }
}

// ---------------------------------------------------------------------------
// Kernel 2: part[kb][d][j] = sum_{k in chunk} yT[d][k]*A[k][j]  (bf16 MFMA)
// KSPLIT=8, NIT=16, double-buffered LDS, ONE barrier per 64-k tile.
// Loads for tile t+1 are in flight across compute of tile t.
// ---------------------------------------------------------------------------
#define BN 128
#define KSPLIT 8
#define KCH (NN / KSPLIT)   // 1024
#define NIT (KCH / 64)      // 16
#define ASZ (64 * 128)
#define YSZ (64 * 72)

__global__ __launch_bounds__(256) void k_spmm(
    const float* __restrict__ A,
    const unsigned short* __restrict__ yT,
    float* __restrict__ part)
{
  __shared__ short Alds[2 * ASZ];   // [buf][k][j swizzled], pitch 128 (256B)
  __shared__ short Ylds[2 * YSZ];   // [buf][d][k], pitch 72 (b128-friendly)

  const int tid  = threadIdx.x;
  const int lane = tid & 63;
  const int wave = tid >> 6;
  const int q    = lane >> 4;    // k-quad within fragment
  const int nn   = lane & 15;    // m (A-frag) / n (B-frag, C col) index

  const int j0     = blockIdx.x * BN;
  const int kstart = blockIdx.y * KCH;

  // A staging: 4 f32 cols (16B) per lane; rows kr + p*8
  const int c4 = tid & 31;
  const int kr = tid >> 5;
  // y staging: 16B chunks; rows m0 + {0,32}
  const int cY = tid & 7;
  const int m0 = tid >> 3;

  const float* ap          = A  + (size_t)(kstart + kr) * NN + j0 + c4 * 4;
  const unsigned short* yp = yT + (size_t)m0 * NN + kstart + cY * 8;

  uint4 abuf[8], ybuf[2];
  auto gload = [&](){
#pragma unroll
    for (int p = 0; p < 8; p++)
      abuf[p] = *(const uint4*)(ap + (size_t)p * 8 * NN);
#pragma unroll
    for (int p = 0; p < 2; p++)
      ybuf[p] = *(const uint4*)(yp + (size_t)p * 32 * NN);
    ap += 64 * NN;   // next 64-k tile
    yp += 64;
  };
  auto stage = [&](int buf){
    short* Ab = &Alds[buf * ASZ];
    short* Yb = &Ylds[buf * YSZ];
#pragma unroll
    for (int p = 0; p < 8; p++){
      const int kk  = kr + p*8;
      const int key = 2 * (p & 3);                 // == 2*((kk>>3)&3), kr<8
      // exact f32->bf16 truncation (A is 0/1), packed two at a time
      unsigned lo = (abuf[p].y & 0xFFFF0000u) | (abuf[p].x >> 16);
      unsigned hi = (abuf[p].w & 0xFFFF0000u) | (abuf[p].z >> 16);
      *(uint2*)(&Ab[kk * 128 + (((c4 >> 1) ^ key) * 8) + (c4 & 1) * 4]) =
          make_uint2(lo, hi);
    }
#pragma unroll
    for (int p = 0; p < 2; p++)
      *(uint4*)(&Yb[(m0 + p*32) * 72 + cY * 8]) = ybuf[p];
  };

  f32x4 acc[4][2];
#pragma unroll
  for (int a = 0; a < 4; a++)
#pragma unroll
    for (int b = 0; b < 2; b++)
      acc[a][b] = (f32x4){0.f, 0.f, 0.f, 0.f};

  gload();
  stage(0);
  __syncthreads();

  for (int it = 0; it < NIT; ++it){
    if (it + 1 < NIT) gload();       // in flight across this tile's compute
    const short* Ab = &Alds[(it & 1) * ASZ];
    const short* Yb = &Ylds[(it & 1) * YSZ];

#pragma unroll
    for (int ks = 0; ks < 2; ks++){
      short8 af[4];
#pragma unroll
      for (int mt = 0; mt < 4; mt++)    // A-frag: yT[m=16mt+nn][k=ks*32+q*8..]
        af[mt] = *(const short8*)(&Yb[(mt*16 + nn) * 72 + ks*32 + q*8]);
#pragma unroll
      for (int nt = 0; nt < 2; nt++){
        const int col = wave * 32 + nt * 16 + nn;
        // B-frag: A[k=ks*32+q*8+jj][col]; swizzle key (k>>3)&3 == q for jj<8
        const short* bp = &Ab[(ks*32 + q*8) * 128
                              + (((col >> 3) ^ (2*q)) * 8) + (col & 7)];
        short8 bf;
#pragma unroll
        for (int jj = 0; jj < 8; jj++) bf[jj] = bp[jj * 128];
#pragma unroll
        for (int mt = 0; mt < 4; mt++)
          acc[mt][nt] = __builtin_amdgcn_mfma_f32_16x16x32_bf16(af[mt], bf, acc[mt][nt], 0, 0, 0);
      }
    }

    if (it + 1 < NIT){
      stage((it + 1) & 1);   // other buffer: safe, all waves passed barrier it-1
      __syncthreads();       // buf (it+1) complete before anyone computes it
    }
  }

  // epilogue: C/D layout col=lane&15, row=q*4+reg; disjoint region, plain stores
  float* pp = part + (size_t)blockIdx.y * DD * NN;
#pragma unroll
  for (int mt = 0; mt < 4; mt++)
#pragma unroll
    for (int nt = 0; nt < 2; nt++)
#pragma unroll
      for (int v = 0; v < 4; v++){
        const int d   = mt * 16 + q * 4 + v;
        const int col = j0 + wave * 32 + nt * 16 + nn;
        pp[(size_t)d * NN + col] = acc[mt][nt][v];
      }
}

// ---------------------------------------------------------------------------
// Kernel 3: out[j][d] = accT[d][j] + sum_kb part[kb][d][j]  (LDS transpose)
// ---------------------------------------------------------------------------
__global__ __launch_bounds__(256) void k_out(
    const float* __restrict__ accT, const float* __restrict__ part,
    float* __restrict__ out)
{
  __shared__ float t[64][33];      // pitch 33: both phases conflict-cheap
  const int tid = threadIdx.x;
  const int jb  = blockIdx.x * 32;

#pragma unroll
  for (int rep = 0; rep < 8; rep++){
    const int d = rep * 8 + (tid >> 5);
    const int j = tid & 31;
    const size_t base = (size_t)d * NN + jb + j;
    float s = accT[base];
#pragma unroll
    for (int kb = 0; kb < KSPLIT; kb++)
      s += part[(size_t)kb * DD * NN + base];
    t[d][j] = s;
  }
  __syncthreads();
#pragma unroll
  for (int rep = 0; rep < 8; rep++){
    const int j = rep * 4 + (tid >> 6);
    const int d = tid & 63;
    out[(size_t)(jb + j) * DD + d] = t[d][j];
  }
}

extern "C" void kernel_launch(void* const* d_in, const int* in_sizes, int n_in,
                              void* d_out, int out_size, void* d_ws, size_t ws_size,
                              hipStream_t stream) {
  const float* x     = (const float*)d_in[0];
  const float* r     = (const float*)d_in[1];
  const float* A     = (const float*)d_in[2];
  const float* Wobj  = (const float*)d_in[3];
  const float* bobj  = (const float*)d_in[4];
  const float* Wnobj = (const float*)d_in[5];
  const float* bnobj = (const float*)d_in[6];
  const float* Wrel  = (const float*)d_in[7];
  const float* brel  = (const float*)d_in[8];
  const float* Wskip = (const float*)d_in[9];
  const float* bskip = (const float*)d_in[10];
  // d_in[11]/d_in[12] (Wa_w/Wa_b) provably unused: softmax rows sum to 1.

  char* ws = (char*)d_ws;
  float* accT        = (float*)ws;                                  // 2 MB
  unsigned short* yT = (unsigned short*)(ws + (size_t)DD*NN*4);     // 1 MB
  float* part        = (float*)(ws + 3u*1024*1024);                 // 16 MB

  k_proj<<<dim3(32, 16), 256, 0, stream>>>(x, r, Wobj, bobj, Wnobj, bnobj,
                                           Wrel, brel, Wskip, bskip, accT, yT);
  k_spmm<<<dim3(NN / BN, KSPLIT), 256, 0, stream>>>(A, yT, part);
  k_out<<<NN / 32, 256, 0, stream>>>(accT, part, (float*)d_out);
}

// Round 7
// 407.207 us; speedup vs baseline: 1.0220x; 1.0180x over previous
//
#include <hip/hip_runtime.h>

typedef __attribute__((ext_vector_type(8))) short short8;
typedef __attribute__((ext_vector_type(4))) float f32x4;
typedef __attribute__((ext_vector_type(4))) unsigned int u32x4;   // native vec: OK for nontemporal builtins

#define NN 8192
#define DD 64

// f32 -> bf16 RNE (internal y staging only)
__device__ inline unsigned short f2bf(float f){
  unsigned b = __float_as_uint(f);
  b = (b + 0x7fffu + ((b >> 16) & 1u)) >> 16;
  return (unsigned short)b;
}

// ---------------------------------------------------------------------------
// Confirmed: inputs f32, output f32, absmax 0.5 vs threshold 1.78.
// Algebra: softmax rows sum to 1 -> attn_agg == aggregated; Wa_* unused.
//   out = x@(Wobj+Wskip) + r@Wrel + A^T @ (x@Wnobj + bnobj) + (bobj+brel+bskip)
// A is exactly 0/1 -> f32->bf16 truncation EXACT -> bf16 MFMA for A^T y.
//
// R7 = R6 with the nontemporal builtin given a native ext_vector type
// (HIP's struct uint4 is rejected). Experiment unchanged: BN=256 (1KB A
// segments, half the stream count) + nontemporal A loads (protect yT L2).
// ---------------------------------------------------------------------------

// Kernel 1: accT[d][i] = x@(Wobj+Wskip)+r@Wrel+biases ; yT[d][i]=bf16(x@Wnobj+bnobj)
__global__ __launch_bounds__(256) void k_proj(
    const float* __restrict__ x, const float* __restrict__ r,
    const float* __restrict__ Wobj,  const float* __restrict__ bobj,
    const float* __restrict__ Wnobj, const float* __restrict__ bnobj,
    const float* __restrict__ Wrel,  const float* __restrict__ brel,
    const float* __restrict__ Wskip, const float* __restrict__ bskip,
    float* __restrict__ accT, unsigned short* __restrict__ yT)
{
  const int i  = blockIdx.x * 256 + threadIdx.x;   // row
  const int d0 = blockIdx.y * 4;                   // 4 output dims

  float ay[4] = {0.f,0.f,0.f,0.f}, az[4] = {0.f,0.f,0.f,0.f};
  const float4* xp = (const float4*)(x + (size_t)i * DD);
  const float4* rp = (const float4*)(r + (size_t)i * DD);

#pragma unroll
  for (int kb = 0; kb < 4; kb++){                  // 16 k per chunk
    float xv[16], rv[16];
#pragma unroll
    for (int p = 0; p < 4; p++){
      float4 u = xp[kb*4 + p];
      xv[4*p+0]=u.x; xv[4*p+1]=u.y; xv[4*p+2]=u.z; xv[4*p+3]=u.w;
      float4 v = rp[kb*4 + p];
      rv[4*p+0]=v.x; rv[4*p+1]=v.y; rv[4*p+2]=v.z; rv[4*p+3]=v.w;
    }
#pragma unroll
    for (int kk = 0; kk < 16; kk++){
      const int wb = (kb*16 + kk) * DD + d0;       // uniform -> s_loads
      const float xk = xv[kk], rk = rv[kk];
#pragma unroll
      for (int t = 0; t < 4; t++){
        ay[t] += xk * Wnobj[wb + t];
        az[t] += xk * Wobj [wb + t];
        az[t] += xk * Wskip[wb + t];
        az[t] += rk * Wrel [wb + t];
      }
    }
  }

#pragma unroll
  for (int t = 0; t < 4; t++){
    ay[t] += bnobj[d0 + t];
    az[t] += bobj[d0 + t] + brel[d0 + t] + bskip[d0 + t];
    yT[(size_t)(d0 + t) * NN + i]   = f2bf(ay[t]);   // coalesced
    accT[(size_t)(d0 + t) * NN + i] = az[t];
  }
}

// ---------------------------------------------------------------------------
// Kernel 2: part[kb][d][j] = sum_{k in chunk} yT[d][k]*A[k][j]  (bf16 MFMA)
// BN=256 (1KB A segments/row), 32-k tiles, double-buffered, KSPLIT=16.
// grid (32 jb, 16 kb) = 512 blocks = 2/CU; LDS 42KB (3 blocks/CU capacity).
// XOR-chunk swizzle: B-frag u16 reads and all staging phases <=2-way (free).
// ---------------------------------------------------------------------------
#define BN 256
#define KSPLIT 16
#define KCH (NN / KSPLIT)    // 512
#define KT 32                // k-depth per tile
#define NIT (KCH / KT)       // 16
#define ASZ (KT * BN)        // 8192 elems (16 KB)
#define YPITCH 40            // 32 + 8: rows 80B = 16B-aligned, af reads 2-way
#define YSZ (DD * YPITCH)    // 2560 elems (5 KB)

__global__ __launch_bounds__(256) void k_spmm(
    const float* __restrict__ A,
    const unsigned short* __restrict__ yT,
    float* __restrict__ part)
{
  __shared__ short Alds[2 * ASZ];
  __shared__ short Ylds[2 * YSZ];

  const int tid  = threadIdx.x;
  const int lane = tid & 63;
  const int wave = tid >> 6;
  const int q    = lane >> 4;    // k-quad within fragment
  const int nn   = lane & 15;    // m (A-frag) / n (B-frag, C col) index

  const int j0     = blockIdx.x * BN;
  const int kstart = blockIdx.y * KCH;

  // A staging: rows kr + 4p (p=0..7), cols c4*4 (16B); wave = 64 contiguous lanes
  const int c4 = tid & 63;       // 4-col chunk within 1KB row
  const int kr = tid >> 6;       // 0..3
  // y staging: 64 m-rows x 4 8-k chunks
  const int cY = tid & 3;
  const int m  = tid >> 2;       // 0..63

  const float* ap          = A  + (size_t)(kstart + kr) * NN + j0 + c4 * 4;
  const unsigned short* yp = yT + (size_t)m * NN + kstart + cY * 8;

  u32x4 abuf[8]; uint4 ybuf;
  auto gload = [&](){
#pragma unroll
    for (int p = 0; p < 8; p++)   // nontemporal: A lines are single-use
      abuf[p] = __builtin_nontemporal_load((const u32x4*)(ap + (size_t)p * 4 * NN));
    ybuf = *(const uint4*)yp;
    ap += (size_t)KT * NN;        // next 32-k tile
    yp += KT;
  };
  auto stage = [&](int buf){
    short* Ab = &Alds[buf * ASZ];
    short* Yb = &Ylds[buf * YSZ];
#pragma unroll
    for (int p = 0; p < 8; p++){
      const int kk  = kr + p*4;                    // 0..31
      const int key = 2 * ((kk >> 3) & 3);
      // exact f32->bf16 truncation (A is 0/1), packed two at a time
      unsigned lo = (abuf[p][1] & 0xFFFF0000u) | (abuf[p][0] >> 16);
      unsigned hi = (abuf[p][3] & 0xFFFF0000u) | (abuf[p][2] >> 16);
      *(uint2*)(&Ab[kk * BN + (((c4 >> 1) ^ key) * 8) + (c4 & 1) * 4]) =
          make_uint2(lo, hi);
    }
    *(uint4*)(&Yb[m * YPITCH + cY * 8]) = ybuf;
  };

  f32x4 acc[4][4];
#pragma unroll
  for (int a = 0; a < 4; a++)
#pragma unroll
    for (int b = 0; b < 4; b++)
      acc[a][b] = (f32x4){0.f, 0.f, 0.f, 0.f};

  gload();
  stage(0);
  __syncthreads();

  for (int it = 0; it < NIT; ++it){
    if (it + 1 < NIT) gload();       // in flight across this tile's compute
    const short* Ab = &Alds[(it & 1) * ASZ];
    const short* Yb = &Ylds[(it & 1) * YSZ];

    short8 af[4];
#pragma unroll
    for (int mt = 0; mt < 4; mt++)    // A-frag: yT[m=16mt+nn][k=q*8..q*8+7]
      af[mt] = *(const short8*)(&Yb[(mt*16 + nn) * YPITCH + q*8]);
#pragma unroll
    for (int nt = 0; nt < 4; nt++){
      const int col = wave * 64 + nt * 16 + nn;
      // B-frag: A[k=q*8+jj][col]; chunk swizzle key (k>>3)&3 == q for jj<8
      const short* bp = &Ab[(q*8) * BN + (((col >> 3) ^ (2*q)) * 8) + (col & 7)];
      short8 bf;
#pragma unroll
      for (int jj = 0; jj < 8; jj++) bf[jj] = bp[jj * BN];
#pragma unroll
      for (int mt = 0; mt < 4; mt++)
        acc[mt][nt] = __builtin_amdgcn_mfma_f32_16x16x32_bf16(af[mt], bf, acc[mt][nt], 0, 0, 0);
    }

    if (it + 1 < NIT){
      stage((it + 1) & 1);   // other buffer: safe, all waves passed barrier it-1
      __syncthreads();       // buf (it+1) complete before anyone computes it
    }
  }

  // epilogue: C/D layout col=lane&15, row=q*4+reg; disjoint region, plain stores
  float* pp = part + (size_t)blockIdx.y * DD * NN;
#pragma unroll
  for (int mt = 0; mt < 4; mt++)
#pragma unroll
    for (int nt = 0; nt < 4; nt++)
#pragma unroll
      for (int v = 0; v < 4; v++){
        const int d   = mt * 16 + q * 4 + v;
        const int col = j0 + wave * 64 + nt * 16 + nn;
        pp[(size_t)d * NN + col] = acc[mt][nt][v];
      }
}

// ---------------------------------------------------------------------------
// Kernel 3: out[j][d] = accT[d][j] + sum_kb part[kb][d][j]  (LDS transpose)
// ---------------------------------------------------------------------------
__global__ __launch_bounds__(256) void k_out(
    const float* __restrict__ accT, const float* __restrict__ part,
    float* __restrict__ out)
{
  __shared__ float t[64][33];      // pitch 33: both phases conflict-cheap
  const int tid = threadIdx.x;
  const int jb  = blockIdx.x * 32;

#pragma unroll
  for (int rep = 0; rep < 8; rep++){
    const int d = rep * 8 + (tid >> 5);
    const int j = tid & 31;
    const size_t base = (size_t)d * NN + jb + j;
    float s = accT[base];
#pragma unroll
    for (int kb = 0; kb < KSPLIT; kb++)
      s += __builtin_nontemporal_load(part + (size_t)kb * DD * NN + base);
    t[d][j] = s;
  }
  __syncthreads();
#pragma unroll
  for (int rep = 0; rep < 8; rep++){
    const int j = rep * 4 + (tid >> 6);
    const int d = tid & 63;
    out[(size_t)(jb + j) * DD + d] = t[d][j];
  }
}

extern "C" void kernel_launch(void* const* d_in, const int* in_sizes, int n_in,
                              void* d_out, int out_size, void* d_ws, size_t ws_size,
                              hipStream_t stream) {
  const float* x     = (const float*)d_in[0];
  const float* r     = (const float*)d_in[1];
  const float* A     = (const float*)d_in[2];
  const float* Wobj  = (const float*)d_in[3];
  const float* bobj  = (const float*)d_in[4];
  const float* Wnobj = (const float*)d_in[5];
  const float* bnobj = (const float*)d_in[6];
  const float* Wrel  = (const float*)d_in[7];
  const float* brel  = (const float*)d_in[8];
  const float* Wskip = (const float*)d_in[9];
  const float* bskip = (const float*)d_in[10];
  // d_in[11]/d_in[12] (Wa_w/Wa_b) provably unused: softmax rows sum to 1.

  char* ws = (char*)d_ws;
  float* accT        = (float*)ws;                                  // 2 MB
  unsigned short* yT = (unsigned short*)(ws + (size_t)DD*NN*4);     // 1 MB
  float* part        = (float*)(ws + 3u*1024*1024);                 // 32 MB

  k_proj<<<dim3(32, 16), 256, 0, stream>>>(x, r, Wobj, bobj, Wnobj, bnobj,
                                           Wrel, brel, Wskip, bskip, accT, yT);
  k_spmm<<<dim3(NN / BN, KSPLIT), 256, 0, stream>>>(A, yT, part);
  k_out<<<NN / 32, 256, 0, stream>>>(accT, part, (float*)d_out);
}